// Round 8
// baseline (388.530 us; speedup 1.0000x reference)
//
#include <hip/hip_runtime.h>

#define CC 100000
#define DD 512

#define S_SCALE 30.0f
#define COS_M_C 0.8775825618903728f
#define SIN_M_C 0.479425538604203f
#define THRESH_C (-0.8775825618903728f)
#define MM_C 0.2397127693021015f

typedef __attribute__((ext_vector_type(8))) short short8;
typedef __attribute__((ext_vector_type(4))) float f32x4;

static __device__ __forceinline__ unsigned short f2bf(float x) {
  unsigned int u = __float_as_uint(x);
  unsigned int r = (u + 0x7fffu + ((u >> 16) & 1u)) >> 16;
  return (unsigned short)r;
}

#define FENCE() __builtin_amdgcn_sched_barrier(0)

// ---------------------------------------------------------------------------
// Kernel 1: per embedding row i: normalize, bf16, store to wsA in MFMA
// FRAGMENT order so k3 can load fragments directly from global:
//   fragment F = kt*32 + wv*4 + mf   (kt = k>>5, wv = i>>6, mf = (i>>4)&3)
//   lane slot q = lg*16 + lr         (lg = (k>>3)&3, lr = i&15)
//   byte addr   = F*1024 + q*16      (16 B = 8 bf16, k-contiguous)
// k1's lane l holds k = 8l..8l+7 of row i -> kt = l>>2, lg = l&3, one store.
// ---------------------------------------------------------------------------
__global__ __launch_bounds__(64) void k1_prep(
    const float* __restrict__ emb, const float* __restrict__ kern,
    const int* __restrict__ label, unsigned short* __restrict__ wsA,
    float* __restrict__ ws_target, float* __restrict__ ws_ctm,
    float* __restrict__ ws_ft) {
  const int i = blockIdx.x;
  const int l = threadIdx.x;

  const float4* er = reinterpret_cast<const float4*>(emb + (size_t)i * DD + l * 8);
  float4 v0 = er[0], v1 = er[1];
  float e[8] = {v0.x, v0.y, v0.z, v0.w, v1.x, v1.y, v1.z, v1.w};

  float esq = 0.f;
#pragma unroll
  for (int j = 0; j < 8; ++j) esq += e[j] * e[j];
#pragma unroll
  for (int o = 32; o > 0; o >>= 1) esq += __shfl_xor(esq, o);
  const float inv = rsqrtf(esq);

  const int c = label[i];
  float dot = 0.f, wsq = 0.f;
#pragma unroll
  for (int j = 0; j < 8; ++j) {
    float w = kern[(size_t)(l * 8 + j) * CC + c];
    dot += e[j] * w;
    wsq += w * w;
  }
#pragma unroll
  for (int o = 32; o > 0; o >>= 1) {
    dot += __shfl_xor(dot, o);
    wsq += __shfl_xor(wsq, o);
  }

  unsigned int pk[4];
#pragma unroll
  for (int j = 0; j < 4; ++j) {
    unsigned int lo = f2bf(e[2 * j] * inv);
    unsigned int hi = f2bf(e[2 * j + 1] * inv);
    pk[j] = lo | (hi << 16);
  }
  // fragment-order address (see header comment)
  const int off = (l >> 2) * 32768 + (i >> 6) * 4096 + (((i >> 4) & 3)) * 1024 +
                  ((l & 3) * 16 + (i & 15)) * 16;
  uint4 v; v.x = pk[0]; v.y = pk[1]; v.z = pk[2]; v.w = pk[3];
  *reinterpret_cast<uint4*>(reinterpret_cast<char*>(wsA) + off) = v;

  if (l == 0) {
    float t = dot * rsqrtf(fmaxf(esq * wsq, 1e-30f));
    t = fminf(fmaxf(t, -1.f), 1.f);
    float st = sqrtf(fmaxf(0.f, 1.f - t * t));
    float ctm = t * COS_M_C - st * SIN_M_C;
    ws_target[i] = t;
    ws_ctm[i] = ctm;
    ws_ft[i] = (t > THRESH_C) ? ctm : (t - MM_C);
  }
}

// ---------------------------------------------------------------------------
// Kernel 2: deterministic reduction of 512 target logits -> t_new
// ---------------------------------------------------------------------------
__global__ __launch_bounds__(64) void k2_tnew(const float* __restrict__ ws_target,
                                              const float* __restrict__ t_in,
                                              float* __restrict__ ws_tnew) {
  const int l = threadIdx.x;
  float s = 0.f;
#pragma unroll
  for (int j = 0; j < 8; ++j) s += ws_target[l * 8 + j];
#pragma unroll
  for (int o = 32; o > 0; o >>= 1) s += __shfl_xor(s, o);
  if (l == 0) ws_tnew[0] = 0.01f * (s * (1.0f / 512.0f)) + 0.99f * t_in[0];
}

// ---------------------------------------------------------------------------
// Kernel 3: 512x64 GEMM + epilogue, restructured:
//  - A fragments loaded DIRECTLY global->VGPR (fragment-order wsA, coalesced
//    dwordx4, L2-hot). No A LDS, no global_load_lds, no A barriers.
//  - B staged in LDS at BK=64: one barrier per 2 K-steps (8 total).
//    Wave wv supplies k-rows wv*8..+7 of its column as ONE ds_write_b128.
//    Chunk swizzle c = (k_local/8) ^ (n&7) -> 2-way max (free, m136).
//  - All global loads are plain C++ (compiler emits counted vmcnt);
//    sched_barrier(0) fences pin issue order; lgkm-only drain + raw
//    s_barrier for cross-wave B visibility (A/B prefetch queue survives
//    the barrier - no vmcnt(0) drain anywhere in the loop).
//  - Every load issued >= 1 full iteration before its use.
// ---------------------------------------------------------------------------
__global__ __launch_bounds__(512, 4) void k3_gemm(
    const float* __restrict__ kern, const unsigned short* __restrict__ wsA,
    const int* __restrict__ label, const float* __restrict__ ws_ctm,
    const float* __restrict__ ws_ft, const float* __restrict__ ws_tnew,
    float* __restrict__ out) {
  __shared__ __align__(16) char smem[34816];  // B bufs 2x8KB; epilogue scratch
  __shared__ float colsq[64];

  const int t = threadIdx.x;
  const int l = t & 63;
  const int wv = t >> 6;
  const int n0 = blockIdx.x * 64;

  if (t < 64) colsq[t] = 0.f;

  const int bn = l;
  const int gcol = n0 + bn;
  const bool colok = gcol < CC;
  const float* bcol = kern + gcol;

  const int lr = l & 15;
  const int lg = l >> 4;

  float sumsq = 0.f;

  f32x4 acc[4][4];
#pragma unroll
  for (int a = 0; a < 4; ++a)
#pragma unroll
    for (int b = 0; b < 4; ++b) acc[a][b] = (f32x4){0.f, 0.f, 0.f, 0.f};

  char* Bb = smem;
  const char* pA0 = reinterpret_cast<const char*>(wsA) + wv * 4096 + l * 16;
  // per-lane LDS offsets: row n stride 128 B, chunk swizzle ^(n&7)==^(lr&7)
  const int rdsw0 = lr * 128 + ((lg ^ (lr & 7)) << 4);        // k-half 0
  const int rdsw1 = lr * 128 + (((4 + lg) ^ (lr & 7)) << 4);  // k-half 1
  const int wroff = bn * 128 + ((wv ^ (bn & 7)) << 4);

  float p0, p1, p2, p3, p4, p5, p6, p7;
  short8 afA[4], afB[4];

#define BLOAD8(KB)                                                       \
  {                                                                      \
    if (colok) {                                                         \
      const float* q_ = bcol + (size_t)(KB) * CC;                        \
      p0 = q_[0];              p1 = q_[(size_t)CC];                      \
      p2 = q_[(size_t)2 * CC]; p3 = q_[(size_t)3 * CC];                  \
      p4 = q_[(size_t)4 * CC]; p5 = q_[(size_t)5 * CC];                  \
      p6 = q_[(size_t)6 * CC]; p7 = q_[(size_t)7 * CC];                  \
    } else {                                                             \
      p0 = p1 = p2 = p3 = p4 = p5 = p6 = p7 = 0.f;                       \
    }                                                                    \
  }

#define BWRITE8(G1)                                                      \
  {                                                                      \
    sumsq += p0 * p0 + p1 * p1 + p2 * p2 + p3 * p3 + p4 * p4 + p5 * p5 + \
             p6 * p6 + p7 * p7;                                          \
    uint4 pk_;                                                           \
    pk_.x = (unsigned int)f2bf(p0) | ((unsigned int)f2bf(p1) << 16);     \
    pk_.y = (unsigned int)f2bf(p2) | ((unsigned int)f2bf(p3) << 16);     \
    pk_.z = (unsigned int)f2bf(p4) | ((unsigned int)f2bf(p5) << 16);     \
    pk_.w = (unsigned int)f2bf(p6) | ((unsigned int)f2bf(p7) << 16);     \
    *reinterpret_cast<uint4*>(Bb + ((G1)&1) * 8192 + wroff) = pk_;       \
  }

#define ALOAD(DST, BYTEOFF)                                              \
  _Pragma("unroll") for (int mf_ = 0; mf_ < 4; ++mf_) DST[mf_] =         \
      *reinterpret_cast<const short8*>(pA0 + (BYTEOFF) + mf_ * 1024);

// 16 MFMA in two nf-halves (bfr kept to 2 frags -> lower reg pressure)
#define MFMA16(AF, BSEL, RDSW)                                           \
  {                                                                      \
    short8 bfr0 =                                                        \
        *reinterpret_cast<const short8*>(Bb + (BSEL) + 0 * 2048 + (RDSW)); \
    short8 bfr1 =                                                        \
        *reinterpret_cast<const short8*>(Bb + (BSEL) + 1 * 2048 + (RDSW)); \
    _Pragma("unroll") for (int mf_ = 0; mf_ < 4; ++mf_) {                \
      acc[mf_][0] = __builtin_amdgcn_mfma_f32_16x16x32_bf16(             \
          AF[mf_], bfr0, acc[mf_][0], 0, 0, 0);                          \
      acc[mf_][1] = __builtin_amdgcn_mfma_f32_16x16x32_bf16(             \
          AF[mf_], bfr1, acc[mf_][1], 0, 0, 0);                          \
    }                                                                    \
    short8 bfr2 =                                                        \
        *reinterpret_cast<const short8*>(Bb + (BSEL) + 2 * 2048 + (RDSW)); \
    short8 bfr3 =                                                        \
        *reinterpret_cast<const short8*>(Bb + (BSEL) + 3 * 2048 + (RDSW)); \
    _Pragma("unroll") for (int mf_ = 0; mf_ < 4; ++mf_) {                \
      acc[mf_][2] = __builtin_amdgcn_mfma_f32_16x16x32_bf16(             \
          AF[mf_], bfr2, acc[mf_][2], 0, 0, 0);                          \
      acc[mf_][3] = __builtin_amdgcn_mfma_f32_16x16x32_bf16(             \
          AF[mf_], bfr3, acc[mf_][3], 0, 0, 0);                          \
    }                                                                    \
  }

  // ---- prologue: stage B group 0, load A(kt=0) ----
  BLOAD8(wv * 8);
  FENCE();
  ALOAD(afA, 0);
  FENCE();
  BWRITE8(0);  // compiler inserts the vmcnt for p* before the pack
  asm volatile("s_waitcnt lgkmcnt(0)" ::: "memory");
  FENCE();
  __builtin_amdgcn_s_barrier();
  FENCE();

  for (int g = 0; g < 8; ++g) {
    const int bsel = (g & 1) * 8192;
    // ---- i=0 (kt=2g): issue next A + next-group B, compute on afA ----
    ALOAD(afB, g * 65536 + 32768);  // A(2g+1)
    if (g < 7) { BLOAD8(64 * (g + 1) + wv * 8); }
    FENCE();
    __builtin_amdgcn_s_setprio(1);
    MFMA16(afA, bsel, rdsw0);
    __builtin_amdgcn_s_setprio(0);
    FENCE();
    // ---- i=1 (kt=2g+1): issue A for next group, commit B, compute afB ----
    if (g < 7) { ALOAD(afA, (g + 1) * 65536); }  // A(2g+2)
    FENCE();
    if (g < 7) { BWRITE8(g + 1); }  // to buf[(g+1)&1], read next group
    __builtin_amdgcn_s_setprio(1);
    MFMA16(afB, bsel, rdsw1);
    __builtin_amdgcn_s_setprio(0);
    asm volatile("s_waitcnt lgkmcnt(0)" ::: "memory");  // drain reads+write
    FENCE();
    __builtin_amdgcn_s_barrier();
    FENCE();
  }

  // ---- column-norm reduce ----
  atomicAdd(&colsq[bn], sumsq);
  asm volatile("s_waitcnt lgkmcnt(0)" ::: "memory");
  FENCE();
  __builtin_amdgcn_s_barrier();
  FENCE();

  const float tnew = ws_tnew[0];
  float invn[4];
#pragma unroll
  for (int nf = 0; nf < 4; ++nf)
    invn[nf] = rsqrtf(fmaxf(colsq[nf * 16 + lr], 1e-30f));

  // ---- epilogue: transpose through wave-private LDS, float4 stores ----
  float* est = reinterpret_cast<float*>(smem) + (size_t)wv * 1088;  // 16x68
  const int c4 = n0 + lr * 4;
#pragma unroll
  for (int mf = 0; mf < 4; ++mf) {
    asm volatile("s_waitcnt lgkmcnt(0)" ::: "memory");  // WAR vs prev reads
    FENCE();
#pragma unroll
    for (int r = 0; r < 4; ++r)
#pragma unroll
      for (int nf = 0; nf < 4; ++nf)
        est[(lg * 4 + r) * 68 + nf * 16 + lr] = acc[mf][nf][r] * invn[nf];
    asm volatile("s_waitcnt lgkmcnt(0)" ::: "memory");  // RAW: writes visible
    FENCE();
#pragma unroll
    for (int p = 0; p < 4; ++p) {
      const int rr = p * 4 + lg;
      const int m = wv * 64 + mf * 16 + rr;
      const float ctm = ws_ctm[m];
      const float ft = ws_ft[m];
      const int lab = label[m];
      float4 vv = *reinterpret_cast<const float4*>(&est[rr * 68 + lr * 4]);
      if (c4 < CC) {
        float ov[4] = {vv.x, vv.y, vv.z, vv.w};
#pragma unroll
        for (int j = 0; j < 4; ++j) {
          float cosv = fminf(fmaxf(ov[j], -1.f), 1.f);
          float val = (cosv > ctm) ? cosv * (tnew + cosv) : cosv;
          if (c4 + j == lab) val = ft;
          ov[j] = val * S_SCALE;
        }
        float4 st4;
        st4.x = ov[0]; st4.y = ov[1]; st4.z = ov[2]; st4.w = ov[3];
        *reinterpret_cast<float4*>(out + (size_t)m * CC + c4) = st4;
      }
    }
  }
#undef BLOAD8
#undef BWRITE8
#undef ALOAD
#undef MFMA16
}

// ---------------------------------------------------------------------------
extern "C" void kernel_launch(void* const* d_in, const int* in_sizes, int n_in,
                              void* d_out, int out_size, void* d_ws,
                              size_t ws_size, hipStream_t stream) {
  (void)in_sizes; (void)n_in; (void)out_size; (void)ws_size;
  const float* emb = (const float*)d_in[0];
  const float* kern = (const float*)d_in[1];
  const int* label = (const int*)d_in[2];
  const float* t_in = (const float*)d_in[3];
  float* out = (float*)d_out;

  char* ws = (char*)d_ws;
  unsigned short* wsA = (unsigned short*)ws;
  float* ws_target = (float*)(ws + 524288);
  float* ws_ctm = (float*)(ws + 526336);
  float* ws_ft = (float*)(ws + 528384);
  float* ws_tnew = (float*)(ws + 530432);

  k1_prep<<<512, 64, 0, stream>>>(emb, kern, label, wsA, ws_target, ws_ctm, ws_ft);
  k2_tnew<<<1, 64, 0, stream>>>(ws_target, t_in, ws_tnew);
  k3_gemm<<<(CC + 63) / 64, 512, 0, stream>>>(kern, wsA, label, ws_ctm, ws_ft,
                                              ws_tnew, out);
}

// Round 9
// 222.593 us; speedup vs baseline: 1.7455x; 1.7455x over previous
//
#include <hip/hip_runtime.h>

#define CC 100000
#define DD 512

#define S_SCALE 30.0f
#define COS_M_C 0.8775825618903728f
#define SIN_M_C 0.479425538604203f
#define THRESH_C (-0.8775825618903728f)
#define MM_C 0.2397127693021015f

typedef __attribute__((ext_vector_type(8))) short short8;
typedef __attribute__((ext_vector_type(4))) float f32x4;
typedef __attribute__((ext_vector_type(4))) unsigned int uint32x4;

static __device__ __forceinline__ unsigned short f2bf(float x) {
  unsigned int u = __float_as_uint(x);
  unsigned int r = (u + 0x7fffu + ((u >> 16) & 1u)) >> 16;
  return (unsigned short)r;
}

#define FENCE() __builtin_amdgcn_sched_barrier(0)

// ---------------------------------------------------------------------------
// Kernel 1: per embedding row i: normalize, bf16, store to wsA in MFMA
// FRAGMENT order (unchanged from round 8, validated):
//   byte addr = (k>>5)*32768 + (i>>6)*4096 + ((i>>4)&3)*1024
//             + (((k>>3)&3)*16 + (i&15))*16
// ---------------------------------------------------------------------------
__global__ __launch_bounds__(64) void k1_prep(
    const float* __restrict__ emb, const float* __restrict__ kern,
    const int* __restrict__ label, unsigned short* __restrict__ wsA,
    float* __restrict__ ws_target, float* __restrict__ ws_ctm,
    float* __restrict__ ws_ft) {
  const int i = blockIdx.x;
  const int l = threadIdx.x;

  const float4* er = reinterpret_cast<const float4*>(emb + (size_t)i * DD + l * 8);
  float4 v0 = er[0], v1 = er[1];
  float e[8] = {v0.x, v0.y, v0.z, v0.w, v1.x, v1.y, v1.z, v1.w};

  float esq = 0.f;
#pragma unroll
  for (int j = 0; j < 8; ++j) esq += e[j] * e[j];
#pragma unroll
  for (int o = 32; o > 0; o >>= 1) esq += __shfl_xor(esq, o);
  const float inv = rsqrtf(esq);

  const int c = label[i];
  float dot = 0.f, wsq = 0.f;
#pragma unroll
  for (int j = 0; j < 8; ++j) {
    float w = kern[(size_t)(l * 8 + j) * CC + c];
    dot += e[j] * w;
    wsq += w * w;
  }
#pragma unroll
  for (int o = 32; o > 0; o >>= 1) {
    dot += __shfl_xor(dot, o);
    wsq += __shfl_xor(wsq, o);
  }

  unsigned int pk[4];
#pragma unroll
  for (int j = 0; j < 4; ++j) {
    unsigned int lo = f2bf(e[2 * j] * inv);
    unsigned int hi = f2bf(e[2 * j + 1] * inv);
    pk[j] = lo | (hi << 16);
  }
  const int off = (l >> 2) * 32768 + (i >> 6) * 4096 + (((i >> 4) & 3)) * 1024 +
                  ((l & 3) * 16 + (i & 15)) * 16;
  uint4 v; v.x = pk[0]; v.y = pk[1]; v.z = pk[2]; v.w = pk[3];
  *reinterpret_cast<uint4*>(reinterpret_cast<char*>(wsA) + off) = v;

  if (l == 0) {
    float t = dot * rsqrtf(fmaxf(esq * wsq, 1e-30f));
    t = fminf(fmaxf(t, -1.f), 1.f);
    float st = sqrtf(fmaxf(0.f, 1.f - t * t));
    float ctm = t * COS_M_C - st * SIN_M_C;
    ws_target[i] = t;
    ws_ctm[i] = ctm;
    ws_ft[i] = (t > THRESH_C) ? ctm : (t - MM_C);
  }
}

// ---------------------------------------------------------------------------
// Kernel 2: deterministic reduction of 512 target logits -> t_new
// ---------------------------------------------------------------------------
__global__ __launch_bounds__(64) void k2_tnew(const float* __restrict__ ws_target,
                                              const float* __restrict__ t_in,
                                              float* __restrict__ ws_tnew) {
  const int l = threadIdx.x;
  float s = 0.f;
#pragma unroll
  for (int j = 0; j < 8; ++j) s += ws_target[l * 8 + j];
#pragma unroll
  for (int o = 32; o > 0; o >>= 1) s += __shfl_xor(s, o);
  if (l == 0) ws_tnew[0] = 0.01f * (s * (1.0f / 512.0f)) + 0.99f * t_in[0];
}

// ---------------------------------------------------------------------------
// Kernel 3: 512x64 GEMM + epilogue. BARRIER-FREE, LDS-FREE main loop:
//  - A fragments: direct global->VGPR from fragment-order wsA (dwordx4,
//    L2/L3-hot).
//  - B fragments: direct global->VGPR in fragment layout (8 fp32 per frag,
//    16-lane x 64B coalesced; each kern element read exactly once
//    chip-wide), v_cvt_pk_bf16_f32 to bf16, consumed immediately.
//  - Column sumsq: per-lane fp32 accumulation + shfl_xor(16,32) reduce.
//    No colsq LDS, no atomics.
//  - Tail block: column index CLAMPED to CC-1 (no branches). Junk columns
//    only affect their own (guarded) outputs: B-frag lane lr feeds output
//    col lr only.
//  - 8 independent waves/block, 4 waves/SIMD: TLP + compiler scheduling
//    hide latency. No manual pipelining (rounds 5/8 proved it spills on
//    top of the 64-AGPR accumulator).
// ---------------------------------------------------------------------------
__global__ __launch_bounds__(512, 4) void k3_gemm(
    const float* __restrict__ kern, const unsigned short* __restrict__ wsA,
    const int* __restrict__ label, const float* __restrict__ ws_ctm,
    const float* __restrict__ ws_ft, const float* __restrict__ ws_tnew,
    float* __restrict__ out) {
  __shared__ __align__(16) float est_all[8][16 * 68];  // epilogue scratch only

  const int t = threadIdx.x;
  const int l = t & 63;
  const int wv = t >> 6;
  const int lr = l & 15;
  const int lg = l >> 4;
  const int n0 = blockIdx.x * 64;

  f32x4 acc[4][4];
#pragma unroll
  for (int a = 0; a < 4; ++a)
#pragma unroll
    for (int b = 0; b < 4; ++b) acc[a][b] = (f32x4){0.f, 0.f, 0.f, 0.f};

  float ssq[4] = {0.f, 0.f, 0.f, 0.f};

  const char* pA = reinterpret_cast<const char*>(wsA) + wv * 4096 + l * 16;
  // B base pointers, one per nf, column clamped (tail block safety)
  const float* pBn[4];
#pragma unroll
  for (int nf = 0; nf < 4; ++nf) {
    int col = n0 + nf * 16 + lr;
    col = col < CC ? col : (CC - 1);
    pBn[nf] = kern + (size_t)(lg * 8) * CC + col;
  }

  for (int kt = 0; kt < 16; ++kt) {
    short8 af[4];
#pragma unroll
    for (int mf = 0; mf < 4; ++mf)
      af[mf] = *reinterpret_cast<const short8*>(pA + kt * 32768 + mf * 1024);
#pragma unroll
    for (int nf = 0; nf < 4; ++nf) {
      const float* q = pBn[nf] + (size_t)kt * 32 * CC;
      float b0 = q[0];
      float b1 = q[(size_t)CC];
      float b2 = q[(size_t)2 * CC];
      float b3 = q[(size_t)3 * CC];
      float b4 = q[(size_t)4 * CC];
      float b5 = q[(size_t)5 * CC];
      float b6 = q[(size_t)6 * CC];
      float b7 = q[(size_t)7 * CC];
      ssq[nf] += b0 * b0 + b1 * b1 + b2 * b2 + b3 * b3 + b4 * b4 + b5 * b5 +
                 b6 * b6 + b7 * b7;
      unsigned int r0, r1, r2, r3;
      asm("v_cvt_pk_bf16_f32 %0, %1, %2" : "=v"(r0) : "v"(b0), "v"(b1));
      asm("v_cvt_pk_bf16_f32 %0, %1, %2" : "=v"(r1) : "v"(b2), "v"(b3));
      asm("v_cvt_pk_bf16_f32 %0, %1, %2" : "=v"(r2) : "v"(b4), "v"(b5));
      asm("v_cvt_pk_bf16_f32 %0, %1, %2" : "=v"(r3) : "v"(b6), "v"(b7));
      uint32x4 pkv = {r0, r1, r2, r3};
      short8 bf = __builtin_bit_cast(short8, pkv);
#pragma unroll
      for (int mf = 0; mf < 4; ++mf)
        acc[mf][nf] = __builtin_amdgcn_mfma_f32_16x16x32_bf16(af[mf], bf,
                                                              acc[mf][nf], 0,
                                                              0, 0);
    }
  }

  // ---- column-norm reduce (wave-local, deterministic) ----
  float invn[4];
#pragma unroll
  for (int nf = 0; nf < 4; ++nf) {
    float s = ssq[nf];
    s += __shfl_xor(s, 16);
    s += __shfl_xor(s, 32);
    invn[nf] = rsqrtf(fmaxf(s, 1e-30f));
  }

  const float tnew = ws_tnew[0];

  // ---- epilogue: transpose through wave-private LDS, float4 stores ----
  float* est = est_all[wv];  // 16x68
  const int c4 = n0 + lr * 4;
#pragma unroll
  for (int mf = 0; mf < 4; ++mf) {
    asm volatile("s_waitcnt lgkmcnt(0)" ::: "memory");  // WAR vs prev reads
    FENCE();
#pragma unroll
    for (int r = 0; r < 4; ++r)
#pragma unroll
      for (int nf = 0; nf < 4; ++nf)
        est[(lg * 4 + r) * 68 + nf * 16 + lr] = acc[mf][nf][r] * invn[nf];
    asm volatile("s_waitcnt lgkmcnt(0)" ::: "memory");  // RAW: writes visible
    FENCE();
#pragma unroll
    for (int p = 0; p < 4; ++p) {
      const int rr = p * 4 + lg;
      const int m = wv * 64 + mf * 16 + rr;
      const float ctm = ws_ctm[m];
      const float ft = ws_ft[m];
      const int lab = label[m];
      float4 vv = *reinterpret_cast<const float4*>(&est[rr * 68 + lr * 4]);
      if (c4 < CC) {
        float ov[4] = {vv.x, vv.y, vv.z, vv.w};
#pragma unroll
        for (int j = 0; j < 4; ++j) {
          float cosv = fminf(fmaxf(ov[j], -1.f), 1.f);
          float val = (cosv > ctm) ? cosv * (tnew + cosv) : cosv;
          if (c4 + j == lab) val = ft;
          ov[j] = val * S_SCALE;
        }
        float4 st4;
        st4.x = ov[0]; st4.y = ov[1]; st4.z = ov[2]; st4.w = ov[3];
        *reinterpret_cast<float4*>(out + (size_t)m * CC + c4) = st4;
      }
    }
  }
}

// ---------------------------------------------------------------------------
extern "C" void kernel_launch(void* const* d_in, const int* in_sizes, int n_in,
                              void* d_out, int out_size, void* d_ws,
                              size_t ws_size, hipStream_t stream) {
  (void)in_sizes; (void)n_in; (void)out_size; (void)ws_size;
  const float* emb = (const float*)d_in[0];
  const float* kern = (const float*)d_in[1];
  const int* label = (const int*)d_in[2];
  const float* t_in = (const float*)d_in[3];
  float* out = (float*)d_out;

  char* ws = (char*)d_ws;
  unsigned short* wsA = (unsigned short*)ws;
  float* ws_target = (float*)(ws + 524288);
  float* ws_ctm = (float*)(ws + 526336);
  float* ws_ft = (float*)(ws + 528384);
  float* ws_tnew = (float*)(ws + 530432);

  k1_prep<<<512, 64, 0, stream>>>(emb, kern, label, wsA, ws_target, ws_ctm, ws_ft);
  k2_tnew<<<1, 64, 0, stream>>>(ws_target, t_in, ws_tnew);
  k3_gemm<<<(CC + 63) / 64, 512, 0, stream>>>(kern, wsA, label, ws_ctm, ws_ft,
                                              ws_tnew, out);
}